// Round 19
// baseline (128.735 us; speedup 1.0000x reference)
//
#include <hip/hip_runtime.h>

// Problem constants (fixed by setup_inputs): B=4096, D=512, H=W=64, N=4096.
#define B_ROWS 4096
#define N_COLS 4096
#define DIM    512
#define LDK    1024   // row stride (elements) of split bf16 arrays [hi(512) | lo(512)]

typedef __attribute__((ext_vector_type(8))) short short8;
typedef __attribute__((ext_vector_type(16))) float floatx16;

// bf16 round-to-nearest-even split helpers (bit-exact, no API dependence)
__device__ __forceinline__ unsigned short f2bf_rn(float f) {
    unsigned u = __float_as_uint(f);
    u += 0x7fffu + ((u >> 16) & 1u);
    return (unsigned short)(u >> 16);
}
__device__ __forceinline__ float bf2f(unsigned short h) {
    return __uint_as_float(((unsigned)h) << 16);
}

// Monotone float->uint map; (key<<32)|idx gives u64 atomicMin argmin with
// smallest-index tie-break (matches numpy argmin semantics).
__device__ __forceinline__ unsigned long long pack_key(float v, int idx) {
    unsigned u = __float_as_uint(v);
    u = (u & 0x80000000u) ? ~u : (u | 0x80000000u);
    return ((unsigned long long)u << 32) | (unsigned)idx;
}

// Async global->LDS, 16B per lane. LDS dest is wave-uniform base + lane*16;
// global source address IS per-lane (m173).
__device__ __forceinline__ void async16(const unsigned short* g, unsigned short* l) {
    __builtin_amdgcn_global_load_lds(
        (__attribute__((address_space(1))) void*)g,
        (__attribute__((address_space(3))) void*)l, 16, 0, 0);
}

// One wave per row (4 rows/block): split fp32 row into bf16 hi/lo halves,
// compute exact fp32 ||row||^2, init packed argmin accumulators. (unchanged)
__global__ __launch_bounds__(256) void som_convert(
    const float* __restrict__ X, const float* __restrict__ Wt,
    unsigned short* __restrict__ Xc, unsigned short* __restrict__ Wc,
    float* __restrict__ x_sq, float* __restrict__ w_sq,
    unsigned long long* __restrict__ packed)
{
    int wave = threadIdx.x >> 6, lane = threadIdx.x & 63;
    int grow = blockIdx.x * 4 + wave;            // 0..8191
    bool isX = grow < B_ROWS;
    const float* src = isX ? (X + (size_t)grow * DIM)
                           : (Wt + (size_t)(grow - B_ROWS) * DIM);
    const float4* p4 = (const float4*)src;
    float4 a = p4[lane * 2], b = p4[lane * 2 + 1];
    float f[8] = {a.x, a.y, a.z, a.w, b.x, b.y, b.z, b.w};
    short8 hi, lo;
    float s = 0.f;
    #pragma unroll
    for (int t = 0; t < 8; ++t) {
        unsigned short h = f2bf_rn(f[t]);
        hi[t] = (short)h;
        lo[t] = (short)f2bf_rn(f[t] - bf2f(h));
        s = fmaf(f[t], f[t], s);
    }
    unsigned short* dst = (isX ? Xc + (size_t)grow * LDK
                               : Wc + (size_t)(grow - B_ROWS) * LDK) + lane * 8;
    *(short8*)(dst)       = hi;
    *(short8*)(dst + 512) = lo;
    #pragma unroll
    for (int off = 32; off >= 1; off >>= 1) s += __shfl_xor(s, off, 64);
    if (lane == 0) {
        if (isX) { x_sq[grow] = s; packed[grow] = ~0ull; }
        else     { w_sq[grow - B_ROWS] = s; }
    }
}

// ---------------------------------------------------------------------------
// Split-bf16 distance GEMM v18 = v17's structure with the MFMA shape changed
// 16x16x32 -> 32x32x16 (the one untried lever):
//  - measured FLOP/cyc: 32x32 shape 4060 vs 16x16 3378 (+21%); per K-step
//    per wave 48 MFMAs x 8.07cyc = 775 SIMD-cyc vs 96 x 4.85 = 931 (-17%)
//  - half the MFMA instruction count -> more issue slots for ds_reads
//  - LDS layout/staging/sync UNCHANGED (v17-verbatim): rotation-coalesced
//    subtile-units, 1 barrier/step, full-step staged-load cover
//  - A/B fragment (k-contiguous convention, as verified for 16x16x32):
//    lane l: row/col = l&31, k = (l>>5)*8+0..7 -> maps onto the 16-row
//    units as u=(l>>4)&1, granule col ((2*k16 + (l>>5) + rot)&3); per
//    quarter-wave each 4-bank group hit exactly 2x -> conflict-free (free)
//  - C/D layout [m74/m101 HW-verified]: col = lane&31,
//    row = (reg&3) + 8*(reg>>2) + 4*(lane>>5), reg in [0,16)
//  - epilogue argmin: 32-lane-group reduce (masks 1..16; never crosses the
//    lane-32 boundary), writer = (lane&31)==0, one atomic per output row
// Geometry: 256x256 block, 8 waves 2x4, 128x64/wave, BK=32, 128KB dbuf.
// Products: hh, ah*bl, al*bh; kt ascending, k16 ascending within each step.
// ---------------------------------------------------------------------------
__global__ __launch_bounds__(512, 2) void som_dist_v18(
    const unsigned short* __restrict__ Xc, const unsigned short* __restrict__ Wc,
    const float* __restrict__ w_sq, unsigned long long* __restrict__ packed)
{
    __shared__ __align__(16) unsigned short L[65536];   // 128 KiB
    const int tid  = threadIdx.x;
    const int wave = tid >> 6, lane = tid & 63;
    const int wr = wave >> 2, wc = wave & 3;       // 2x4 wave grid, 128x64/wave
    const int bm = blockIdx.y, bn = blockIdx.x;

    // Cooperative staging (v17-verbatim): wave stages subtile-units
    // s = wave*4+q (q=0..3) of each region per K-tile (rsub=s>>1, h=s&1).
    const int srow = lane >> 2;
    const int scol = ((((lane & 3) - ((lane >> 3) & 3)) & 3)) * 8;
    const unsigned short* gAq[4];
    const unsigned short* gBq[4];
    #pragma unroll
    for (int q = 0; q < 4; ++q) {
        const int s = wave * 4 + q, rsub = s >> 1, h = s & 1;
        gAq[q] = Xc + (size_t)(bm * 256 + rsub * 16 + srow) * LDK + h * 512 + scol;
        gBq[q] = Wc + (size_t)(bn * 256 + rsub * 16 + srow) * LDK + h * 512 + scol;
    }

    // 32x32x16 fragment addressing within the rotation layout:
    // lane l needs row/col l&31 (unit u=(l>>4)&1, row-in-unit r=l&15),
    // k = (l>>5)*8 within the k16-half => granule col ((2*k16+kx+rot)&3).
    const int r15 = lane & 15;
    const int u   = (lane >> 4) & 1;
    const int kx  = lane >> 5;
    const int rot = (r15 >> 1) & 3;
    const int fragbase = u * 1024 + r15 * 32;          // shorts
    const int ck[2] = { ((kx + rot) & 3) * 8, ((kx + 2 + rot) & 3) * 8 };

    floatx16 acc[4][2];
    #pragma unroll
    for (int i = 0; i < 4; ++i)
        #pragma unroll
        for (int j = 0; j < 2; ++j)
            #pragma unroll
            for (int r = 0; r < 16; ++r) acc[i][j][r] = 0.f;

    // Prologue (v17-verbatim): stage tile 0 only (B then A).
    #pragma unroll
    for (int q = 0; q < 4; ++q) async16(gBq[q], &L[32768 + (wave * 4 + q) * 512]);
    #pragma unroll
    for (int q = 0; q < 4; ++q) async16(gAq[q], &L[(wave * 4 + q) * 512]);

    #pragma unroll 1
    for (int kt = 0; kt < 16; ++kt) {
        const int slot = kt & 1;

        // Single per-step sync point (v17): lgkm0 (prev reads retired),
        // vmcnt0 (tile kt staged, loads had a full step of cover), barrier.
        asm volatile("s_waitcnt lgkmcnt(0)" ::: "memory");
        asm volatile("s_waitcnt vmcnt(0)" ::: "memory");
        __builtin_amdgcn_s_barrier();
        asm volatile("" ::: "memory");

        // Stage tile kt+1 into slot^1 (held tile kt-1; reads retired).
        if (kt < 15) {
            unsigned short* RB = &L[32768 + (slot ^ 1) * 16384];
            unsigned short* RA = &L[(slot ^ 1) * 16384];
            const int k1 = (kt + 1) * 32;
            #pragma unroll
            for (int q = 0; q < 4; ++q) async16(gBq[q] + k1, RB + (wave * 4 + q) * 512);
            #pragma unroll
            for (int q = 0; q < 4; ++q) async16(gAq[q] + k1, RA + (wave * 4 + q) * 512);
        }

        const unsigned short* pA = &L[slot * 16384 + wr * 8192 + fragbase];
        const unsigned short* pB = &L[32768 + slot * 16384 + wc * 4096 + fragbase];
        short8 ah[4][2], bh[2][2], bl[2][2], al[4][2];

        // Cluster 1: ah x bh (k16 ascending inside each acc)
        #pragma unroll
        for (int i = 0; i < 4; ++i)
            #pragma unroll
            for (int k = 0; k < 2; ++k)
                ah[i][k] = *(const short8*)(pA + i * 2048 + ck[k]);
        #pragma unroll
        for (int j = 0; j < 2; ++j)
            #pragma unroll
            for (int k = 0; k < 2; ++k)
                bh[j][k] = *(const short8*)(pB + j * 2048 + ck[k]);
        __builtin_amdgcn_s_setprio(1);
        #pragma unroll
        for (int i = 0; i < 4; ++i)
            #pragma unroll
            for (int j = 0; j < 2; ++j)
                #pragma unroll
                for (int k = 0; k < 2; ++k)
                    acc[i][j] = __builtin_amdgcn_mfma_f32_32x32x16_bf16(
                        ah[i][k], bh[j][k], acc[i][j], 0, 0, 0);
        __builtin_amdgcn_s_setprio(0);

        // Cluster 2: ah x bl
        #pragma unroll
        for (int j = 0; j < 2; ++j)
            #pragma unroll
            for (int k = 0; k < 2; ++k)
                bl[j][k] = *(const short8*)(pB + j * 2048 + 512 + ck[k]);
        __builtin_amdgcn_s_setprio(1);
        #pragma unroll
        for (int i = 0; i < 4; ++i)
            #pragma unroll
            for (int j = 0; j < 2; ++j)
                #pragma unroll
                for (int k = 0; k < 2; ++k)
                    acc[i][j] = __builtin_amdgcn_mfma_f32_32x32x16_bf16(
                        ah[i][k], bl[j][k], acc[i][j], 0, 0, 0);
        __builtin_amdgcn_s_setprio(0);

        // Cluster 3: al x bh
        #pragma unroll
        for (int i = 0; i < 4; ++i)
            #pragma unroll
            for (int k = 0; k < 2; ++k)
                al[i][k] = *(const short8*)(pA + i * 2048 + 512 + ck[k]);
        __builtin_amdgcn_s_setprio(1);
        #pragma unroll
        for (int i = 0; i < 4; ++i)
            #pragma unroll
            for (int j = 0; j < 2; ++j)
                #pragma unroll
                for (int k = 0; k < 2; ++k)
                    acc[i][j] = __builtin_amdgcn_mfma_f32_32x32x16_bf16(
                        al[i][k], bh[j][k], acc[i][j], 0, 0, 0);
        __builtin_amdgcn_s_setprio(0);
    }

    // Epilogue: val = w_sq - 2*dot. 32x32 C/D layout [m74/m101]:
    // col = lane&31, row = (reg&3) + 8*(reg>>2) + 4*(lane>>5).
    const int colL = lane & 31;
    const int hi5  = lane >> 5;
    const int col0 = bn * 256 + wc * 64 + colL;
    float wq[2];
    wq[0] = w_sq[col0];
    wq[1] = w_sq[col0 + 32];
    const int row_base = bm * 256 + wr * 128 + hi5 * 4;
    #pragma unroll
    for (int i = 0; i < 4; ++i) {
        #pragma unroll
        for (int r = 0; r < 16; ++r) {
            unsigned long long best = ~0ull;
            #pragma unroll
            for (int j = 0; j < 2; ++j) {
                float val = fmaf(-2.f, acc[i][j][r], wq[j]);
                unsigned long long key = pack_key(val, col0 + j * 32);
                best = (key < best) ? key : best;
            }
            #pragma unroll
            for (int m = 1; m <= 16; m <<= 1) {    // reduce 32-lane col group
                unsigned long long o = __shfl_xor(best, m, 64);
                best = (o < best) ? o : best;
            }
            if (colL == 0)
                atomicMin(&packed[row_base + i * 32 + (r & 3) + 8 * (r >> 2)], best);
        }
    }
}

// Unpack argmin, qe = sqrt(max(||x||^2 + val, 0)).
// d_out: bmu_indices (4096 x 2) flat, then qe (4096), all float. (unchanged)
__global__ __launch_bounds__(256) void som_finalize(
    const unsigned long long* __restrict__ packed,
    const float* __restrict__ x_sq, float* __restrict__ out)
{
    int b = blockIdx.x * 256 + threadIdx.x;  // 0..4095
    unsigned long long p = packed[b];
    unsigned idx = (unsigned)(p & 0xffffffffull);
    unsigned key = (unsigned)(p >> 32);
    unsigned u = (key & 0x80000000u) ? (key & 0x7fffffffu) : ~key;
    float val = __uint_as_float(u);
    float sq = fmaxf(x_sq[b] + val, 0.f);
    out[2 * b]     = (float)(idx >> 6);   // y = idx / 64
    out[2 * b + 1] = (float)(idx & 63);   // x = idx % 64
    out[2 * B_ROWS + b] = sqrtf(sq);
}

extern "C" void kernel_launch(void* const* d_in, const int* in_sizes, int n_in,
                              void* d_out, int out_size, void* d_ws, size_t ws_size,
                              hipStream_t stream) {
    const float* X  = (const float*)d_in[0];   // (4096, 512)
    const float* Wt = (const float*)d_in[1];   // (64, 64, 512) -> (4096, 512)
    float* out = (float*)d_out;

    // ws layout: [0,32K) packed u64[4096]; [32K,48K) x_sq; [48K,64K) w_sq;
    // [64K, 64K+8M) Xc bf16 split; [64K+8M, 64K+16M) Wc bf16 split.
    unsigned long long* packed = (unsigned long long*)d_ws;
    float* x_sq = (float*)((char*)d_ws + (32 << 10));
    float* w_sq = (float*)((char*)d_ws + (48 << 10));
    unsigned short* Xc = (unsigned short*)((char*)d_ws + (64 << 10));
    unsigned short* Wc = (unsigned short*)((char*)d_ws + (64 << 10) + ((size_t)B_ROWS * LDK * 2));

    som_convert<<<dim3((B_ROWS + N_COLS) / 4), dim3(256), 0, stream>>>(
        X, Wt, Xc, Wc, x_sq, w_sq, packed);
    som_dist_v18<<<dim3(N_COLS / 256, B_ROWS / 256), dim3(512), 0, stream>>>(
        Xc, Wc, w_sq, packed);
    som_finalize<<<dim3(B_ROWS / 256), dim3(256), 0, stream>>>(packed, x_sq, out);
}